// Round 7
// baseline (416.269 us; speedup 1.0000x reference)
//
#include <hip/hip_runtime.h>
#include <stdint.h>

// Binarized ConvNet via XOR+popcount on packed bits.
// conv1 is factored through its 25-bit input windows: kA stores win[196] per
// image (6.4 MB) and computes BN1 stats by readlane-recompute (no LDS);
// kB recomputes/binarizes conv1 from win, then does conv2; kC does fc; kD BN3.

#define NB 8192
typedef unsigned long long ull;

// ---- ws layout ----
#define OFF_WIN ((size_t)0)                    // u32 [NB][256] (196 used)
#define SZ_WIN  ((size_t)NB*1024)
#define OFF_C2  (OFF_WIN + SZ_WIN)             // int8 [NB][64ch][64pos] (o/2)
#define SZ_C2   ((size_t)NB*4096)
#define OFF_FC  (OFF_C2 + SZ_C2)               // int32 [NB][10]
#define SZ_FC   ((size_t)NB*10*4)
#define OFF_S1  (OFF_FC + SZ_FC)               // int  [8][32][2]   2048 B
#define OFF_S2  (OFF_S1 + 2048)                // ull  [8][64][2]   8192 B
#define OFF_S3  (OFF_S2 + 8192)                // ull  [8][10][2]   (pad 2048)
#define OFF_W2B (OFF_S3 + 2048)                // ull w2bT[8][64] (word-idx major)
#define OFF_W3B (OFF_W2B + 4096)               // ull w3b[10][64ch], bit=pos

// exact integer threshold: bit = (v >= T) ^ flip  <=>  s*v + t > 0
__device__ inline void mk_thresh(double s, double t, int &T, int &flip) {
    if (s > 0.0) {
        int v = (int)floor(-t / s) - 2;
        for (int c = 0; c < 6; ++c) { if (s * (double)v + t > 0.0) break; ++v; }
        T = v; flip = 0;
    } else if (s < 0.0) {
        int v = (int)floor(-t / s) - 2;
        for (int c = 0; c < 6; ++c) { if (!(s * (double)v + t > 0.0)) break; ++v; }
        T = v; flip = 1;
    } else { T = -200; flip = (t > 0.0) ? 0 : 1; }
}
__device__ inline int clampT(int T, int lim) {
    return (T < -lim) ? -lim : (T > lim) ? lim : T;
}

// vm/nv for conv1 position p (compile-time under full unroll)
__device__ __forceinline__ void pos_consts(int p, uint32_t &vm, int &nv) {
    const int i = p / 14, j = p - 14*i;
    const uint32_t cmask = (j == 0) ? 0x1Cu : (j == 13) ? 0x0Fu : 0x1Fu;
    vm = 0u;
    #pragma unroll
    for (int u = 0; u < 5; ++u) {
        const int r = 2*i + u - 2;
        if (r >= 0 && r < 28) vm |= cmask << (5*u);
    }
    nv = __popc(vm);
}

// ------------------------------------------------------------------
// KA: build conv1 windows win[196] + integer BN1 stats (readlane recompute).
// 1 wave = 1 image, 4/block, no barriers.  Block 2048 packs w2/w3 bits.
// ------------------------------------------------------------------
__global__ __launch_bounds__(256) void kA_conv1(
    const float* __restrict__ x, const float* __restrict__ w1,
    const float* __restrict__ w2, const float* __restrict__ w3,
    uint32_t* __restrict__ wing, int* __restrict__ stats1,
    ull* __restrict__ w2bT, ull* __restrict__ w3b)
{
    const int tid = threadIdx.x, lane = tid & 63, wv = tid >> 6;

    if (blockIdx.x == 2048) {   // ---- weight packer block ----
        for (int m = wv; m < 10; m += 4) {
            const float* wp = w3 + (size_t)m*4096;
            ull mine = 0ull;
            for (int ch = 0; ch < 64; ++ch) {
                const ull bal = __ballot(wp[(size_t)ch*64 + lane] > 0.f);
                if (lane == ch) mine = bal;
            }
            w3b[m*64 + lane] = mine;
        }
        for (int t = tid; t < 512; t += 256) {
            const int idx = t >> 6, k = t & 63;
            const int u = idx >> 1, pr = idx & 1;
            uint32_t lo = 0u, hi = 0u;
            for (int c = 0; c < 32; ++c) {
                const float* wp = w2 + (((k*32 + c)*4 + u)*4 + 2*pr);
                lo |= (wp[0] > 0.f ? 1u : 0u) << c;
                hi |= (wp[1] > 0.f ? 1u : 0u) << c;
            }
            w2bT[t] = (ull)lo | ((ull)hi << 32);
        }
        return;
    }

    __shared__ ull sxb[4][16];              // 784 input sign bits, per wave
    const int n = blockIdx.x*4 + wv;

    // own channel's 25-bit filter (halves duplicate)
    uint32_t wf = 0u;
    {
        const int c = lane & 31;
        #pragma unroll
        for (int q = 0; q < 25; ++q) wf |= (w1[c*25 + q] > 0.f ? 1u : 0u) << q;
    }
    // phase A: 13 ballots -> lane-distributed words (predicated select)
    uint32_t blo = 0u, bhi = 0u;
    #pragma unroll
    for (int t = 0; t < 13; ++t) {
        const int idx = t*64 + lane;
        const float v = (idx < 784) ? x[(size_t)n*784 + idx] : -1.f;
        const ull bal = __ballot(v > 0.f);
        blo = (lane == t) ? (uint32_t)bal : blo;
        bhi = (lane == t) ? (uint32_t)(bal >> 32) : bhi;
    }
    if (lane < 14) sxb[wv][lane] = (lane < 13) ? (((ull)bhi << 32) | blo) : 0ull;
    // phase B: each lane builds win for up to 4 positions
    uint32_t win_t[4];
    #pragma unroll
    for (int t = 0; t < 4; ++t) {
        const int p = t*64 + lane;
        uint32_t win = 0u;
        if (p < 196) {
            const int i = p / 14, j = p - i*14;
            #pragma unroll
            for (int u = 0; u < 5; ++u) {
                const int r = 2*i + u - 2;
                const int rc = (r < 0) ? 0 : (r > 27) ? 27 : r;
                const int bp = 28*rc, w0 = bp >> 6, sh = bp & 63;
                const ull a = sxb[wv][w0], b = sxb[wv][w0+1];
                uint32_t row = (uint32_t)((a >> sh) | ((b << 1) << (63 - sh)));
                row = (row & 0x0FFFFFFFu) << 2;
                const uint32_t bits = ((row >> (2*j)) & 31u) << (5*u);
                win |= (r >= 0 && r < 28) ? bits : 0u;
            }
            wing[(size_t)n*256 + p] = win;
        }
        win_t[t] = win;
    }
    // stats: recompute o per channel via uniform readlane (no LDS)
    int s = 0, q = 0;
    #pragma unroll
    for (int p = 0; p < 196; ++p) {
        const uint32_t WW = (uint32_t)__builtin_amdgcn_readlane((int)win_t[p >> 6], p & 63);
        uint32_t vm; int nv; pos_consts(p, vm, nv);
        const int d = __popc((WW ^ wf) & vm);
        const int o = nv - 2*d;
        s += o; q += o*o;
    }
    if (lane < 32) {
        const int shard = (blockIdx.x*4 + wv) & 7;
        atomicAdd(&stats1[(shard*32 + lane)*2 + 0], s);
        atomicAdd(&stats1[(shard*32 + lane)*2 + 1], q);
    }
}

// ------------------------------------------------------------------
// KB: per-wave BN1 integer thresholds, recompute+binarize conv1 from win
// (ballot), conv2 xor+popc (lane=out-ch, fully unrolled), register BN2
// stats, int8 o/2 out [n][ch][pos].  1 wave = 1 image, no barriers.
// ------------------------------------------------------------------
__global__ __launch_bounds__(256) void kB_conv2(
    const uint32_t* __restrict__ wing, const float* __restrict__ w1,
    const int* __restrict__ stats1,
    const float* __restrict__ gm1, const float* __restrict__ bt1,
    const ull* __restrict__ w2bT,
    int8_t* __restrict__ c2out, ull* __restrict__ stats2)
{
    __shared__ uint32_t Bw[4][256];     // position-words, per wave
    const int tid = threadIdx.x, lane = tid & 63, wv = tid >> 6;
    const int n = blockIdx.x*4 + wv;

    // W fragments straight from global (coalesced, L2-hot)
    ull W[8];
    #pragma unroll
    for (int idx = 0; idx < 8; ++idx) W[idx] = w2bT[idx*64 + lane];

    // own channel filter + BN1 integer threshold (halves duplicate)
    const int c = lane & 31;
    uint32_t wf = 0u;
    #pragma unroll
    for (int qq = 0; qq < 25; ++qq) wf |= (w1[c*25 + qq] > 0.f ? 1u : 0u) << qq;
    int T1, fl;
    {
        long long ss = 0, qs = 0;
        for (int sh = 0; sh < 8; ++sh) {
            ss += stats1[(sh*32 + c)*2 + 0];
            qs += stats1[(sh*32 + c)*2 + 1];
        }
        const double N = 8192.0 * 196.0;
        const double mean = (double)ss / N;
        const double var  = (double)qs / N - mean*mean;
        const double a = (double)gm1[c] / sqrt(var + 1e-5);
        const double b = (double)bt1[c] - mean*a;
        int T; mk_thresh(a, b, T, fl);
        T1 = clampT(T, 26);
    }
    const uint32_t flipw = (uint32_t)__ballot(fl != 0);
    // per-nv-class popcount thresholds: bit = (d <= thr) ^ flip
    const int thr9  = (9  - T1) >> 1, thr12 = (12 - T1) >> 1;
    const int thr15 = (15 - T1) >> 1, thr16 = (16 - T1) >> 1;
    const int thr20 = (20 - T1) >> 1, thr25 = (25 - T1) >> 1;

    // load own image's windows (196 used, padded to 256)
    uint32_t wint[4];
    #pragma unroll
    for (int t = 0; t < 4; ++t) wint[t] = wing[(size_t)n*256 + t*64 + lane];

    // pack: recompute conv1, binarize, ballot -> position word (predicated)
    uint32_t bw0 = 0u, bw1 = 0u, bw2 = 0u, bw3 = 0u;
    #pragma unroll
    for (int p = 0; p < 196; ++p) {
        const uint32_t WW = (uint32_t)__builtin_amdgcn_readlane((int)wint[p >> 6], p & 63);
        uint32_t vm; int nv; pos_consts(p, vm, nv);
        const int d = __popc((WW ^ wf) & vm);
        const int thr = (nv == 9) ? thr9 : (nv == 12) ? thr12 : (nv == 15) ? thr15
                      : (nv == 16) ? thr16 : (nv == 20) ? thr20 : thr25;
        const uint32_t word = (uint32_t)__ballot(d <= thr) ^ flipw;
        const int t = p >> 6, l = p & 63;
        const bool sel = (lane == l);
        if (t == 0)      bw0 = sel ? word : bw0;
        else if (t == 1) bw1 = sel ? word : bw1;
        else if (t == 2) bw2 = sel ? word : bw2;
        else             bw3 = sel ? word : bw3;
    }
    Bw[wv][0*64 + lane] = bw0;
    Bw[wv][1*64 + lane] = bw1;
    Bw[wv][2*64 + lane] = bw2;
    Bw[wv][3*64 + lane] = bw3;   // garbage beyond 195 never read
    __builtin_amdgcn_s_waitcnt(0);   // wave-local LDS visibility

    // compute phase: lane = out-channel, fully unrolled over 64 positions
    int s = 0, q = 0;
    uint32_t od[16];
    #pragma unroll
    for (int i = 0; i < 8; ++i) {
        uint32_t packA = 0u;
        #pragma unroll
        for (int j = 0; j < 8; ++j) {
            int D = 0, nw = 0;
            #pragma unroll
            for (int u = 0; u < 4; ++u) {
                const int r = 2*i + u - 2;
                if (r < 0 || r > 13) continue;           // compile-time
                if (j >= 1) { D += __popcll(*(const ull*)&Bw[wv][r*14 + 2*j - 2] ^ W[2*u+0]); ++nw; }
                if (j <= 6) { D += __popcll(*(const ull*)&Bw[wv][r*14 + 2*j]     ^ W[2*u+1]); ++nw; }
            }
            const int o = 32*nw - D;                     // = full/2, exact
            s += o; q += o*o;
            packA |= (uint32_t)(o & 255) << (8*(j & 3));
            if ((j & 3) == 3) { od[2*i + (j >> 2)] = packA; packA = 0u; }
        }
    }
    {   // writeout [n][ch][pos]: 16 dword stores, stride 64 B across lanes
        uint32_t* dst = (uint32_t*)(c2out + (size_t)n*4096) + lane*16;
        #pragma unroll
        for (int t = 0; t < 16; ++t) dst[t] = od[t];
    }
    {
        const int shard = (blockIdx.x*4 + wv) & 7;
        atomicAdd(&stats2[(shard*64 + lane)*2 + 0], (ull)(long long)s);
        atomicAdd(&stats2[(shard*64 + lane)*2 + 1], (ull)(long long)q);
    }
}

// ------------------------------------------------------------------
// KC: per-lane BN2 thresholds (lane=ch, registers only), binarize
// arithmetically, fc xor+popc, packed shuffle reduction, BN3 stats.
// 1 wave = 1 image.
// ------------------------------------------------------------------
__global__ __launch_bounds__(256) void kC_fc(
    const int8_t* __restrict__ c2o, const float* __restrict__ gm2,
    const float* __restrict__ bt2, const ull* __restrict__ stats2,
    const ull* __restrict__ w3b,
    int* __restrict__ fc, ull* __restrict__ stats3)
{
    __shared__ int fco[4][10];
    __shared__ int s3[10], q3[10];
    const int tid = threadIdx.x, lane = tid & 63, wv = tid >> 6;
    if (tid < 10) { s3[tid] = 0; q3[tid] = 0; }
    // per-lane BN2 threshold for own channel (values stored are o/2)
    int T2, fl;
    {
        long long ss = 0, qq = 0;
        for (int sh = 0; sh < 8; ++sh) {
            ss += (long long)stats2[(sh*64 + lane)*2 + 0];
            qq += (long long)stats2[(sh*64 + lane)*2 + 1];
        }
        const double N = 8192.0 * 64.0;
        const double mh = (double)ss / N;
        const double vh = (double)qq / N - mh*mh;
        const double a = (double)gm2[lane] / sqrt(4.0*vh + 1e-5);
        const double b = (double)bt2[lane] - 2.0*mh*a;
        int T; mk_thresh(2.0*a, b, T, fl);
        T2 = clampT(T, 200);
    }
    const ull flipn2 = ~__ballot(fl != 0);
    const int n = blockIdx.x*4 + wv;
    // load own channel's 64 bytes, build bit-word arithmetically
    const uint4* src = (const uint4*)(c2o + (size_t)n*4096 + lane*64);
    uint32_t neglo = 0u, neghi = 0u;
    #pragma unroll
    for (int r4 = 0; r4 < 4; ++r4) {
        const uint4 v4 = src[r4];
        const uint32_t wsrc[4] = {v4.x, v4.y, v4.z, v4.w};
        #pragma unroll
        for (int cc = 0; cc < 4; ++cc) {
            #pragma unroll
            for (int b = 0; b < 4; ++b) {
                const int p = r4*16 + cc*4 + b;
                const int v = (int)((int8_t)(wsrc[cc] >> (8*b)));
                const uint32_t bit = (uint32_t)(v - T2) >> 31;   // 1 iff v<T
                if (p < 32) neglo |= bit << p; else neghi |= bit << (p - 32);
            }
        }
    }
    const ull myw = ((ull)neglo | ((ull)neghi << 32)) ^ flipn2;
    // 10 outputs: popc of mismatch vs w3 words (global, L2-hot), packed reduce
    uint32_t pk[5];
    #pragma unroll
    for (int t = 0; t < 5; ++t) {
        const uint32_t pa = (uint32_t)__popcll(myw ^ w3b[(2*t+0)*64 + lane]);
        const uint32_t pb = (uint32_t)__popcll(myw ^ w3b[(2*t+1)*64 + lane]);
        pk[t] = pa | (pb << 16);
    }
    #pragma unroll
    for (int off = 32; off >= 1; off >>= 1) {
        #pragma unroll
        for (int t = 0; t < 5; ++t) pk[t] += __shfl_xor(pk[t], off);
    }
    if (lane == 0) {
        #pragma unroll
        for (int m = 0; m < 10; ++m) {
            const int tot = (pk[m >> 1] >> (16*(m & 1))) & 0xFFFF;
            fco[wv][m] = 4096 - 2*tot;
        }
    }
    __syncthreads();
    if (tid < 40) {
        const int li = tid / 10, m = tid - li*10;
        const int o = fco[li][m];
        fc[(size_t)(blockIdx.x*4 + li)*10 + m] = o;
        atomicAdd(&s3[m], o);
        atomicAdd(&q3[m], o*o);
    }
    __syncthreads();
    if (tid < 10) {
        const int shard = blockIdx.x & 7;
        atomicAdd(&stats3[(shard*10 + tid)*2 + 0], (ull)(long long)s3[tid]);
        atomicAdd(&stats3[(shard*10 + tid)*2 + 1], (ull)(long long)q3[tid]);
    }
}

// ------------------------------------------------------------------
// KD: reduce BN3 stats (per block, redundant) + apply -> d_out (fp32)
// ------------------------------------------------------------------
__global__ __launch_bounds__(256) void kD_apply(
    const int* __restrict__ fc, const float* __restrict__ gm3,
    const float* __restrict__ bt3, const ull* __restrict__ stats3,
    float* __restrict__ out)
{
    __shared__ float a3[10], b3[10];
    const int tid = threadIdx.x;
    if (tid < 10) {
        long long s = 0, q = 0;
        for (int sh = 0; sh < 8; ++sh) {
            s += (long long)stats3[(sh*10 + tid)*2 + 0];
            q += (long long)stats3[(sh*10 + tid)*2 + 1];
        }
        const double N = 8192.0;
        const double mean = (double)s / N;
        const double var  = (double)q / N - mean*mean;
        const double a = (double)gm3[tid] / sqrt(var + 1e-5);
        a3[tid] = (float)a;
        b3[tid] = (float)((double)bt3[tid] - mean*a);
    }
    __syncthreads();
    const int e = blockIdx.x*256 + tid;
    if (e < NB*10) {
        const int m = e % 10;
        out[e] = fmaf(a3[m], (float)fc[e], b3[m]);
    }
}

extern "C" void kernel_launch(void* const* d_in, const int* in_sizes, int n_in,
                              void* d_out, int out_size, void* d_ws, size_t ws_size,
                              hipStream_t stream)
{
    const float* x   = (const float*)d_in[0];
    const float* w1  = (const float*)d_in[1];
    const float* gm1 = (const float*)d_in[2];
    const float* bt1 = (const float*)d_in[3];
    const float* w2  = (const float*)d_in[4];
    const float* gm2 = (const float*)d_in[5];
    const float* bt2 = (const float*)d_in[6];
    const float* w3  = (const float*)d_in[7];
    const float* gm3 = (const float*)d_in[8];
    const float* bt3 = (const float*)d_in[9];
    char* ws = (char*)d_ws;
    uint32_t* wing = (uint32_t*)(ws + OFF_WIN);
    int8_t* c2o = (int8_t*)(ws + OFF_C2);
    int*    fcb = (int*)(ws + OFF_FC);
    int*    s1  = (int*)(ws + OFF_S1);
    ull*    s2  = (ull*)(ws + OFF_S2);
    ull*    s3  = (ull*)(ws + OFF_S3);
    ull*    w2bp = (ull*)(ws + OFF_W2B);
    ull*    w3bp = (ull*)(ws + OFF_W3B);

    (void)hipMemsetAsync(ws + OFF_S1, 0, 12288, stream);
    kA_conv1<<<2049, 256, 0, stream>>>(x, w1, w2, w3, wing, s1, w2bp, w3bp);
    kB_conv2<<<2048, 256, 0, stream>>>(wing, w1, s1, gm1, bt1, w2bp, c2o, s2);
    kC_fc   <<<2048, 256, 0, stream>>>(c2o, gm2, bt2, s2, w3bp, fcb, s3);
    kD_apply<<<320,  256, 0, stream>>>(fcb, gm3, bt3, s3, (float*)d_out);
}

// Round 8
// 188.959 us; speedup vs baseline: 2.2030x; 2.2030x over previous
//
#include <hip/hip_runtime.h>
#include <stdint.h>

// Binarized ConvNet via XOR+popcount on packed bits.
// BN stats = exact integer sums (sharded global atomics); BN+sign folded into
// exact per-channel integer thresholds, computed redundantly per consumer
// block/wave.  Heavy kernels are wave-independent; kB keeps its binarized
// feature map in a register sliding window (rows loaded once from LDS).

#define NB 8192
typedef unsigned long long ull;

// ---- ws layout ----
#define OFF_C1  ((size_t)0)                    // int8 [NB][196pos][32ch]
#define SZ_C1   ((size_t)NB*6272)
#define OFF_C2  (OFF_C1 + SZ_C1)               // int8 [NB][64ch][64pos] (o/2)
#define SZ_C2   ((size_t)NB*4096)
#define OFF_FC  (OFF_C2 + SZ_C2)               // int32 [NB][10]
#define SZ_FC   ((size_t)NB*10*4)
#define OFF_S1  (OFF_FC + SZ_FC)               // int  [8][32][2]   2048 B
#define OFF_S2  (OFF_S1 + 2048)                // ull  [8][64][2]   8192 B
#define OFF_S3  (OFF_S2 + 8192)                // ull  [8][10][2]   (pad 2048)
#define OFF_W2B (OFF_S3 + 2048)                // ull w2bT[8][64] (word-idx major)
#define OFF_W3B (OFF_W2B + 4096)               // ull w3b[10][64ch], bit=pos

// exact integer threshold: bit = (v >= T) ^ flip  <=>  s*v + t > 0
__device__ inline void mk_thresh(double s, double t, int &T, int &flip) {
    if (s > 0.0) {
        int v = (int)floor(-t / s) - 2;
        for (int c = 0; c < 6; ++c) { if (s * (double)v + t > 0.0) break; ++v; }
        T = v; flip = 0;
    } else if (s < 0.0) {
        int v = (int)floor(-t / s) - 2;
        for (int c = 0; c < 6; ++c) { if (!(s * (double)v + t > 0.0)) break; ++v; }
        T = v; flip = 1;
    } else { T = -200; flip = (t > 0.0) ? 0 : 1; }
}
__device__ inline int clampT(int T, int lim) {
    return (T < -lim) ? -lim : (T > lim) ? lim : T;
}

// ------------------------------------------------------------------
// KA: conv1 (binary) + integer BN1 stats.  1 wave = 1 image, 4/block.
// Direct register->global c1 store; stats via dword LDS reads + shfl.
// Block 2048 packs w2/w3 sign bits.
// ------------------------------------------------------------------
__global__ __launch_bounds__(256) void kA_conv1(
    const float* __restrict__ x, const float* __restrict__ w1,
    const float* __restrict__ w2, const float* __restrict__ w3,
    int8_t* __restrict__ c1out, int* __restrict__ stats1,
    ull* __restrict__ w2bT, ull* __restrict__ w3b)
{
    const int tid = threadIdx.x, lane = tid & 63, wv = tid >> 6;

    if (blockIdx.x == 2048) {   // ---- weight packer block ----
        for (int m = wv; m < 10; m += 4) {
            const float* wp = w3 + (size_t)m*4096;
            ull mine = 0ull;
            for (int ch = 0; ch < 64; ++ch) {
                const ull bal = __ballot(wp[(size_t)ch*64 + lane] > 0.f);
                if (lane == ch) mine = bal;
            }
            w3b[m*64 + lane] = mine;
        }
        for (int t = tid; t < 512; t += 256) {
            const int idx = t >> 6, k = t & 63;
            const int u = idx >> 1, pr = idx & 1;
            uint32_t lo = 0u, hi = 0u;
            for (int c = 0; c < 32; ++c) {
                const float* wp = w2 + (((k*32 + c)*4 + u)*4 + 2*pr);
                lo |= (wp[0] > 0.f ? 1u : 0u) << c;
                hi |= (wp[1] > 0.f ? 1u : 0u) << c;
            }
            w2bT[t] = (ull)lo | ((ull)hi << 32);
        }
        return;
    }

    __shared__ ull sxb[4][16];              // 784 input sign bits, per wave
    __shared__ uint32_t wfilt[32];          // 25-bit filters
    __shared__ uint32_t outb[4][1568];      // int8 [196][32] as dwords, per wave
    __shared__ int lsum[32], lsq[32];

    if (tid < 32) {
        uint32_t f = 0u;
        #pragma unroll
        for (int q = 0; q < 25; ++q) f |= (w1[tid*25 + q] > 0.f ? 1u : 0u) << q;
        wfilt[tid] = f;
        lsum[tid] = 0; lsq[tid] = 0;
    }
    __syncthreads();          // barrier 1: wfilt + zeroed lsum visible
    const int n = blockIdx.x*4 + wv;
    // phase A: pack 784 input sign bits (13 ballot rounds) — wave-local
    #pragma unroll
    for (int t = 0; t < 13; ++t) {
        const int idx = t*64 + lane;
        const float v = (idx < 784) ? x[(size_t)n*784 + idx] : -1.f;
        const ull bal = __ballot(v > 0.f);
        if (lane == t) sxb[wv][t] = bal;
    }
    if (lane == 13) sxb[wv][13] = 0ull;
    // phase B: each lane computes up to 4 positions, 32 channels each;
    // writes LDS (for stats) and global (direct) from registers
    for (int t = 0; t < 4; ++t) {
        const int p = t*64 + lane;
        if (p < 196) {
            const int i = p / 14, j = p - i*14;
            const uint32_t cmask = (j == 0) ? 0x1Cu : (j == 13) ? 0x0Fu : 0x1Fu;
            uint32_t win = 0u, vm = 0u;
            #pragma unroll
            for (int u = 0; u < 5; ++u) {
                const int r = 2*i + u - 2;
                if (r >= 0 && r < 28) {
                    const int bp = 28*r, w0 = bp >> 6, sh = bp & 63;
                    const ull a = sxb[wv][w0], b = sxb[wv][w0+1];
                    uint32_t row = (uint32_t)((a >> sh) | ((b << 1) << (63 - sh)));
                    row = (row & 0x0FFFFFFFu) << 2;
                    win |= ((row >> (2*j)) & 31u) << (5*u);
                    vm  |= cmask << (5*u);
                }
            }
            const int nv = __popc(vm);
            uint32_t dw[8];
            #pragma unroll
            for (int d = 0; d < 8; ++d) dw[d] = 0u;
            #pragma unroll
            for (int c = 0; c < 32; ++c) {
                const int diff = __popc((win ^ wfilt[c]) & vm);
                const int o = nv - 2*diff;
                dw[c >> 2] |= (uint32_t)(o & 255) << (8*(c & 3));
            }
            #pragma unroll
            for (int d = 0; d < 8; ++d) outb[wv][p*8 + d] = dw[d];
            uint4* dst = (uint4*)(c1out + (size_t)n*6272 + (size_t)p*32);
            dst[0] = make_uint4(dw[0], dw[1], dw[2], dw[3]);
            dst[1] = make_uint4(dw[4], dw[5], dw[6], dw[7]);
        }
    }
    {   // stats: dword reads, lane owns channel-dword d = lane&7
        int s4[4] = {0,0,0,0}, q4[4] = {0,0,0,0};
        const uint32_t* ob32 = &outb[wv][0];
        #pragma unroll
        for (int t = 0; t < 25; ++t) {
            const int idx = t*64 + lane;
            if (idx < 1568) {
                const uint32_t dwv = ob32[idx];
                #pragma unroll
                for (int qq = 0; qq < 4; ++qq) {
                    const int v = (int)((int8_t)(dwv >> (8*qq)));
                    s4[qq] += v; q4[qq] += v*v;
                }
            }
        }
        #pragma unroll
        for (int off = 8; off <= 32; off <<= 1) {
            #pragma unroll
            for (int qq = 0; qq < 4; ++qq) {
                s4[qq] += __shfl_xor(s4[qq], off);
                q4[qq] += __shfl_xor(q4[qq], off);
            }
        }
        if (lane < 8) {
            #pragma unroll
            for (int qq = 0; qq < 4; ++qq) {
                atomicAdd(&lsum[lane*4 + qq], s4[qq]);
                atomicAdd(&lsq[lane*4 + qq], q4[qq]);
            }
        }
    }
    __syncthreads();          // barrier 2: all waves' stats in lsum/lsq
    if (tid < 32) {
        const int shard = blockIdx.x & 7;
        atomicAdd(&stats1[(shard*32 + tid)*2 + 0], lsum[tid]);
        atomicAdd(&stats1[(shard*32 + tid)*2 + 1], lsq[tid]);
    }
}

// ------------------------------------------------------------------
// KB: per-wave BN1 thresholds (packed byte regs), binarize c1, conv2
// xor+popc with REGISTER sliding-window rows (each Bw row read once from
// LDS as broadcast), int8 o/2 out [n][ch][pos].  1 wave = 1 image.
// ------------------------------------------------------------------
__global__ __launch_bounds__(256, 4) void kB_conv2(
    const int8_t* __restrict__ c1out, const int* __restrict__ stats1,
    const float* __restrict__ gm1, const float* __restrict__ bt1,
    const ull* __restrict__ w2bT,
    int8_t* __restrict__ c2out, ull* __restrict__ stats2)
{
    __shared__ uint32_t Bw[4][14][16];  // packed input bits, 14 dwords used/row
    __shared__ int ssum[64], ssq[64];
    const int tid = threadIdx.x, lane = tid & 63, wv = tid >> 6;
    const int n = blockIdx.x*4 + wv;

    // W fragments from global (coalesced, L2-hot), split lo/hi dwords
    uint32_t Wlo[8], Whi[8];
    #pragma unroll
    for (int idx = 0; idx < 8; ++idx) {
        const uint2 w = ((const uint2*)w2bT)[idx*64 + lane];
        Wlo[idx] = w.x; Whi[idx] = w.y;
    }
    if (tid < 64) { ssum[tid] = 0; ssq[tid] = 0; }

    // per-wave BN1 integer thresholds -> 8 packed byte registers
    const int c = lane & 31;
    int T1, fl;
    {
        long long ss = 0, qs = 0;
        for (int sh = 0; sh < 8; ++sh) {
            ss += stats1[(sh*32 + c)*2 + 0];
            qs += stats1[(sh*32 + c)*2 + 1];
        }
        const double N = 8192.0 * 196.0;
        const double mean = (double)ss / N;
        const double var  = (double)qs / N - mean*mean;
        const double a = (double)gm1[c] / sqrt(var + 1e-5);
        const double b = (double)bt1[c] - mean*a;
        int T; mk_thresh(a, b, T, fl);
        T1 = clampT(T, 26);
    }
    const uint32_t flipn1 = ~(uint32_t)__ballot((lane < 32) && (fl != 0));
    uint32_t tp[8];
    {
        uint32_t myb = ((uint32_t)(T1 & 255)) << (8*(lane & 3));
        myb |= __shfl_xor(myb, 1);
        myb |= __shfl_xor(myb, 2);
        #pragma unroll
        for (int k = 0; k < 8; ++k) tp[k] = __shfl(myb, 4*k);
    }
    __syncthreads();          // ssum zeros visible (thresholds wave-local)

    // pack phase — wave-local: binarize own image's 196 positions
    for (int t = lane; t < 196; t += 64) {
        const int r = t / 14, cc = t - r*14;
        const uint4* src = (const uint4*)(c1out + ((size_t)n*196 + t)*32);
        const uint4 lo4 = src[0], hi4 = src[1];
        const uint32_t wsrc[8] = {lo4.x, lo4.y, lo4.z, lo4.w, hi4.x, hi4.y, hi4.z, hi4.w};
        uint32_t neg = 0u;
        #pragma unroll
        for (int d = 0; d < 8; ++d) {
            #pragma unroll
            for (int qq = 0; qq < 4; ++qq) {
                const int ch = d*4 + qq;
                const int v = (int)((int8_t)(wsrc[d] >> (8*qq)));
                const int T = (int)((int8_t)(tp[d] >> (8*qq)));
                neg |= ((uint32_t)(v - T) >> 31) << ch;   // 1 iff v<T
            }
        }
        Bw[wv][r][cc] = neg ^ flipn1;
    }
    __builtin_amdgcn_s_waitcnt(0);   // wave-local LDS visibility

    // compute: register sliding window, pair k = rows(2k,2k+1) in buf[k&1]
    uint32_t bufA[28], bufB[28];
#define LOADPAIR(BUF, K)                                            \
    {                                                               \
        _Pragma("unroll")                                           \
        for (int t2 = 0; t2 < 14; ++t2) {                           \
            BUF[t2]      = Bw[wv][2*(K)][t2];                       \
            BUF[14 + t2] = Bw[wv][2*(K)+1][t2];                     \
        }                                                           \
    }
#define UTERM(BUF, BASE, UU)                                                          \
    {                                                                                 \
        if (j >= 1) { D += __popc(BUF[(BASE)+2*j-2] ^ Wlo[2*(UU)])                    \
                         + __popc(BUF[(BASE)+2*j-1] ^ Whi[2*(UU)]);   ++nw; }         \
        if (j <= 6) { D += __popc(BUF[(BASE)+2*j]   ^ Wlo[2*(UU)+1])                  \
                         + __popc(BUF[(BASE)+2*j+1] ^ Whi[2*(UU)+1]); ++nw; }         \
    }
    int s = 0, q = 0;
    int8_t* outbase = c2out + (size_t)n*4096 + lane*64;
    #pragma unroll
    for (int i = 0; i < 8; ++i) {
        if (i == 0) { LOADPAIR(bufA, 0) }
        else if (i < 7) {
            if (i & 1) { LOADPAIR(bufB, i) } else { LOADPAIR(bufA, i) }
        }
        uint32_t o0 = 0u, o1 = 0u;
        #pragma unroll
        for (int j = 0; j < 8; ++j) {
            int D = 0, nw = 0;
            if (i >= 1) {          // u=0,1 on pair i-1
                if ((i-1) & 1) { UTERM(bufB, 0, 0) UTERM(bufB, 14, 1) }
                else           { UTERM(bufA, 0, 0) UTERM(bufA, 14, 1) }
            }
            if (i <= 6) {          // u=2,3 on pair i
                if (i & 1) { UTERM(bufB, 0, 2) UTERM(bufB, 14, 3) }
                else       { UTERM(bufA, 0, 2) UTERM(bufA, 14, 3) }
            }
            const int o = 32*nw - D;         // = full/2, exact
            s += o; q += o*o;
            if (j < 4) o0 |= (uint32_t)(o & 255) << (8*j);
            else       o1 |= (uint32_t)(o & 255) << (8*(j-4));
        }
        *(uint2*)(outbase + i*8) = make_uint2(o0, o1);
    }
#undef LOADPAIR
#undef UTERM
    atomicAdd(&ssum[lane], s);
    atomicAdd(&ssq[lane], q);
    __syncthreads();          // all waves' stats in ssum/ssq
    if (tid < 64) {
        const int shard = blockIdx.x & 7;
        atomicAdd(&stats2[(shard*64 + tid)*2 + 0], (ull)(long long)ssum[tid]);
        atomicAdd(&stats2[(shard*64 + tid)*2 + 1], (ull)(long long)ssq[tid]);
    }
}

// ------------------------------------------------------------------
// KC: per-lane BN2 thresholds (lane=ch, registers only), binarize
// arithmetically, fc xor+popc, packed shuffle reduction, BN3 stats.
// 1 wave = 1 image.
// ------------------------------------------------------------------
__global__ __launch_bounds__(256) void kC_fc(
    const int8_t* __restrict__ c2o, const float* __restrict__ gm2,
    const float* __restrict__ bt2, const ull* __restrict__ stats2,
    const ull* __restrict__ w3b,
    int* __restrict__ fc, ull* __restrict__ stats3)
{
    __shared__ int fco[4][10];
    __shared__ int s3[10], q3[10];
    const int tid = threadIdx.x, lane = tid & 63, wv = tid >> 6;
    if (tid < 10) { s3[tid] = 0; q3[tid] = 0; }
    // per-lane BN2 threshold for own channel (values stored are o/2)
    int T2, fl;
    {
        long long ss = 0, qq = 0;
        for (int sh = 0; sh < 8; ++sh) {
            ss += (long long)stats2[(sh*64 + lane)*2 + 0];
            qq += (long long)stats2[(sh*64 + lane)*2 + 1];
        }
        const double N = 8192.0 * 64.0;
        const double mh = (double)ss / N;
        const double vh = (double)qq / N - mh*mh;
        const double a = (double)gm2[lane] / sqrt(4.0*vh + 1e-5);
        const double b = (double)bt2[lane] - 2.0*mh*a;
        int T; mk_thresh(2.0*a, b, T, fl);
        T2 = clampT(T, 200);
    }
    const ull flipn2 = ~__ballot(fl != 0);
    const int n = blockIdx.x*4 + wv;
    // load own channel's 64 bytes, build bit-word arithmetically
    const uint4* src = (const uint4*)(c2o + (size_t)n*4096 + lane*64);
    uint32_t neglo = 0u, neghi = 0u;
    #pragma unroll
    for (int r4 = 0; r4 < 4; ++r4) {
        const uint4 v4 = src[r4];
        const uint32_t wsrc[4] = {v4.x, v4.y, v4.z, v4.w};
        #pragma unroll
        for (int cc = 0; cc < 4; ++cc) {
            #pragma unroll
            for (int b = 0; b < 4; ++b) {
                const int p = r4*16 + cc*4 + b;
                const int v = (int)((int8_t)(wsrc[cc] >> (8*b)));
                const uint32_t bit = (uint32_t)(v - T2) >> 31;   // 1 iff v<T
                if (p < 32) neglo |= bit << p; else neghi |= bit << (p - 32);
            }
        }
    }
    const ull myw = ((ull)neglo | ((ull)neghi << 32)) ^ flipn2;
    // 10 outputs: popc of mismatch vs w3 words (global, L2-hot), packed reduce
    uint32_t pk[5];
    #pragma unroll
    for (int t = 0; t < 5; ++t) {
        const uint32_t pa = (uint32_t)__popcll(myw ^ w3b[(2*t+0)*64 + lane]);
        const uint32_t pb = (uint32_t)__popcll(myw ^ w3b[(2*t+1)*64 + lane]);
        pk[t] = pa | (pb << 16);
    }
    #pragma unroll
    for (int off = 32; off >= 1; off >>= 1) {
        #pragma unroll
        for (int t = 0; t < 5; ++t) pk[t] += __shfl_xor(pk[t], off);
    }
    if (lane == 0) {
        #pragma unroll
        for (int m = 0; m < 10; ++m) {
            const int tot = (pk[m >> 1] >> (16*(m & 1))) & 0xFFFF;
            fco[wv][m] = 4096 - 2*tot;
        }
    }
    __syncthreads();
    if (tid < 40) {
        const int li = tid / 10, m = tid - li*10;
        const int o = fco[li][m];
        fc[(size_t)(blockIdx.x*4 + li)*10 + m] = o;
        atomicAdd(&s3[m], o);
        atomicAdd(&q3[m], o*o);
    }
    __syncthreads();
    if (tid < 10) {
        const int shard = blockIdx.x & 7;
        atomicAdd(&stats3[(shard*10 + tid)*2 + 0], (ull)(long long)s3[tid]);
        atomicAdd(&stats3[(shard*10 + tid)*2 + 1], (ull)(long long)q3[tid]);
    }
}

// ------------------------------------------------------------------
// KD: reduce BN3 stats (per block, redundant) + apply -> d_out (fp32)
// ------------------------------------------------------------------
__global__ __launch_bounds__(256) void kD_apply(
    const int* __restrict__ fc, const float* __restrict__ gm3,
    const float* __restrict__ bt3, const ull* __restrict__ stats3,
    float* __restrict__ out)
{
    __shared__ float a3[10], b3[10];
    const int tid = threadIdx.x;
    if (tid < 10) {
        long long s = 0, q = 0;
        for (int sh = 0; sh < 8; ++sh) {
            s += (long long)stats3[(sh*10 + tid)*2 + 0];
            q += (long long)stats3[(sh*10 + tid)*2 + 1];
        }
        const double N = 8192.0;
        const double mean = (double)s / N;
        const double var  = (double)q / N - mean*mean;
        const double a = (double)gm3[tid] / sqrt(var + 1e-5);
        a3[tid] = (float)a;
        b3[tid] = (float)((double)bt3[tid] - mean*a);
    }
    __syncthreads();
    const int e = blockIdx.x*256 + tid;
    if (e < NB*10) {
        const int m = e % 10;
        out[e] = fmaf(a3[m], (float)fc[e], b3[m]);
    }
}

extern "C" void kernel_launch(void* const* d_in, const int* in_sizes, int n_in,
                              void* d_out, int out_size, void* d_ws, size_t ws_size,
                              hipStream_t stream)
{
    const float* x   = (const float*)d_in[0];
    const float* w1  = (const float*)d_in[1];
    const float* gm1 = (const float*)d_in[2];
    const float* bt1 = (const float*)d_in[3];
    const float* w2  = (const float*)d_in[4];
    const float* gm2 = (const float*)d_in[5];
    const float* bt2 = (const float*)d_in[6];
    const float* w3  = (const float*)d_in[7];
    const float* gm3 = (const float*)d_in[8];
    const float* bt3 = (const float*)d_in[9];
    char* ws = (char*)d_ws;
    int8_t* c1o = (int8_t*)(ws + OFF_C1);
    int8_t* c2o = (int8_t*)(ws + OFF_C2);
    int*    fcb = (int*)(ws + OFF_FC);
    int*    s1  = (int*)(ws + OFF_S1);
    ull*    s2  = (ull*)(ws + OFF_S2);
    ull*    s3  = (ull*)(ws + OFF_S3);
    ull*    w2bp = (ull*)(ws + OFF_W2B);
    ull*    w3bp = (ull*)(ws + OFF_W3B);

    (void)hipMemsetAsync(ws + OFF_S1, 0, 12288, stream);
    kA_conv1<<<2049, 256, 0, stream>>>(x, w1, w2, w3, c1o, s1, w2bp, w3bp);
    kB_conv2<<<2048, 256, 0, stream>>>(c1o, s1, gm1, bt1, w2bp, c2o, s2);
    kC_fc   <<<2048, 256, 0, stream>>>(c2o, gm2, bt2, s2, w3bp, fcb, s3);
    kD_apply<<<320,  256, 0, stream>>>(fcb, gm3, bt3, s3, (float*)d_out);
}

// Round 9
// 182.573 us; speedup vs baseline: 2.2800x; 1.0350x over previous
//
#include <hip/hip_runtime.h>
#include <stdint.h>

// Binarized ConvNet via XOR+popcount on packed bits.
// BN stats = exact integer sums (sharded global atomics); BN+sign folded into
// exact per-channel integer thresholds, computed redundantly per consumer wave.
// kP packs weights (thread-per-word, no serial tail); kA conv1; kB conv2
// (R5-proven LDS-staged form); kC fc; kD BN3-apply.

#define NB 8192
typedef unsigned long long ull;

// ---- ws layout ----
#define OFF_C1  ((size_t)0)                    // int8 [NB][196pos][32ch]
#define SZ_C1   ((size_t)NB*6272)
#define OFF_C2  (OFF_C1 + SZ_C1)               // int8 [NB][64ch][64pos] (o/2)
#define SZ_C2   ((size_t)NB*4096)
#define OFF_FC  (OFF_C2 + SZ_C2)               // int32 [NB][10]
#define SZ_FC   ((size_t)NB*10*4)
#define OFF_S1  (OFF_FC + SZ_FC)               // int  [8][32][2]   2048 B
#define OFF_S2  (OFF_S1 + 2048)                // ull  [8][64][2]   8192 B
#define OFF_S3  (OFF_S2 + 8192)                // ull  [8][10][2]   (pad 2048)
#define OFF_W2B (OFF_S3 + 2048)                // ull w2bT[8][64] (word-idx major)
#define OFF_W3B (OFF_W2B + 4096)               // ull w3b[10][64ch], bit=pos

// exact integer threshold: bit = (v >= T) ^ flip  <=>  s*v + t > 0
__device__ inline void mk_thresh(double s, double t, int &T, int &flip) {
    if (s > 0.0) {
        int v = (int)floor(-t / s) - 2;
        for (int c = 0; c < 6; ++c) { if (s * (double)v + t > 0.0) break; ++v; }
        T = v; flip = 0;
    } else if (s < 0.0) {
        int v = (int)floor(-t / s) - 2;
        for (int c = 0; c < 6; ++c) { if (!(s * (double)v + t > 0.0)) break; ++v; }
        T = v; flip = 1;
    } else { T = -200; flip = (t > 0.0) ? 0 : 1; }
}
__device__ inline int clampT(int T, int lim) {
    return (T < -lim) ? -lim : (T > lim) ? lim : T;
}

// ------------------------------------------------------------------
// KP: weight packer — one THREAD per packed word, fully parallel.
// t < 512: w2bT word; 512 <= t < 1152: w3b word.
// ------------------------------------------------------------------
__global__ __launch_bounds__(256) void kP_pack(
    const float* __restrict__ w2, const float* __restrict__ w3,
    ull* __restrict__ w2bT, ull* __restrict__ w3b)
{
    const int t = blockIdx.x*256 + threadIdx.x;
    if (t < 512) {
        const int idx = t >> 6, k = t & 63;
        const int u = idx >> 1, pr = idx & 1;
        uint32_t lo = 0u, hi = 0u;
        #pragma unroll 8
        for (int c = 0; c < 32; ++c) {
            const float* wp = w2 + (((k*32 + c)*4 + u)*4 + 2*pr);
            lo |= (wp[0] > 0.f ? 1u : 0u) << c;
            hi |= (wp[1] > 0.f ? 1u : 0u) << c;
        }
        w2bT[t] = (ull)lo | ((ull)hi << 32);
    } else if (t < 1152) {
        const int w = t - 512;                 // w = m*64 + ch
        const float* wp = w3 + (size_t)(w >> 6)*4096 + (size_t)(w & 63)*64;
        ull bits = 0ull;
        #pragma unroll 16
        for (int k = 0; k < 64; ++k)
            bits |= (ull)(wp[k] > 0.f ? 1 : 0) << k;
        w3b[w] = bits;
    }
}

// ------------------------------------------------------------------
// KA: conv1 (binary) + integer BN1 stats.  1 wave = 1 image, 4/block.
// LDS-staged coalesced writes; dword stats reads + shfl reduce.
// ------------------------------------------------------------------
__global__ __launch_bounds__(256) void kA_conv1(
    const float* __restrict__ x, const float* __restrict__ w1,
    int8_t* __restrict__ c1out, int* __restrict__ stats1)
{
    const int tid = threadIdx.x, lane = tid & 63, wv = tid >> 6;

    __shared__ ull sxb[4][16];              // 784 input sign bits, per wave
    __shared__ uint32_t wfilt[32];          // 25-bit filters
    __shared__ uint32_t outb[4][1568];      // int8 [196][32] as dwords, per wave
    __shared__ int lsum[32], lsq[32];

    if (tid < 32) {
        uint32_t f = 0u;
        #pragma unroll
        for (int q = 0; q < 25; ++q) f |= (w1[tid*25 + q] > 0.f ? 1u : 0u) << q;
        wfilt[tid] = f;
        lsum[tid] = 0; lsq[tid] = 0;
    }
    __syncthreads();          // barrier 1: wfilt + zeroed lsum visible
    const int n = blockIdx.x*4 + wv;
    // phase A: pack 784 input sign bits (13 ballot rounds) — wave-local
    #pragma unroll
    for (int t = 0; t < 13; ++t) {
        const int idx = t*64 + lane;
        const float v = (idx < 784) ? x[(size_t)n*784 + idx] : -1.f;
        const ull bal = __ballot(v > 0.f);
        if (lane == t) sxb[wv][t] = bal;
    }
    if (lane == 13) sxb[wv][13] = 0ull;
    // phase B: each lane computes up to 4 positions, 32 channels each
    for (int t = 0; t < 4; ++t) {
        const int p = t*64 + lane;
        if (p < 196) {
            const int i = p / 14, j = p - i*14;
            const uint32_t cmask = (j == 0) ? 0x1Cu : (j == 13) ? 0x0Fu : 0x1Fu;
            uint32_t win = 0u, vm = 0u;
            #pragma unroll
            for (int u = 0; u < 5; ++u) {
                const int r = 2*i + u - 2;
                if (r >= 0 && r < 28) {
                    const int bp = 28*r, w0 = bp >> 6, sh = bp & 63;
                    const ull a = sxb[wv][w0], b = sxb[wv][w0+1];
                    uint32_t row = (uint32_t)((a >> sh) | ((b << 1) << (63 - sh)));
                    row = (row & 0x0FFFFFFFu) << 2;
                    win |= ((row >> (2*j)) & 31u) << (5*u);
                    vm  |= cmask << (5*u);
                }
            }
            const int nv = __popc(vm);
            uint32_t dw[8];
            #pragma unroll
            for (int d = 0; d < 8; ++d) dw[d] = 0u;
            #pragma unroll
            for (int c = 0; c < 32; ++c) {
                const int diff = __popc((win ^ wfilt[c]) & vm);
                const int o = nv - 2*diff;
                dw[c >> 2] |= (uint32_t)(o & 255) << (8*(c & 3));
            }
            #pragma unroll
            for (int d = 0; d < 8; ++d) outb[wv][p*8 + d] = dw[d];
        }
    }
    {   // coalesced write [n][pos][ch] — wave-local, from LDS staging
        int4* dst = (int4*)(c1out + (size_t)n*6272);
        const int4* src = (const int4*)&outb[wv][0];
        #pragma unroll
        for (int t = 0; t < 7; ++t) {
            const int idx = t*64 + lane;
            if (idx < 392) dst[idx] = src[idx];
        }
    }
    {   // stats: dword reads, lane owns channel-dword d = lane&7
        int s4[4] = {0,0,0,0}, q4[4] = {0,0,0,0};
        const uint32_t* ob32 = &outb[wv][0];
        #pragma unroll
        for (int t = 0; t < 25; ++t) {
            const int idx = t*64 + lane;
            if (idx < 1568) {
                const uint32_t dwv = ob32[idx];
                #pragma unroll
                for (int qq = 0; qq < 4; ++qq) {
                    const int v = (int)((int8_t)(dwv >> (8*qq)));
                    s4[qq] += v; q4[qq] += v*v;
                }
            }
        }
        #pragma unroll
        for (int off = 8; off <= 32; off <<= 1) {
            #pragma unroll
            for (int qq = 0; qq < 4; ++qq) {
                s4[qq] += __shfl_xor(s4[qq], off);
                q4[qq] += __shfl_xor(q4[qq], off);
            }
        }
        if (lane < 8) {
            #pragma unroll
            for (int qq = 0; qq < 4; ++qq) {
                atomicAdd(&lsum[lane*4 + qq], s4[qq]);
                atomicAdd(&lsq[lane*4 + qq], q4[qq]);
            }
        }
    }
    __syncthreads();          // barrier 2: all waves' stats in lsum/lsq
    if (tid < 32) {
        const int shard = blockIdx.x & 7;
        atomicAdd(&stats1[(shard*32 + tid)*2 + 0], lsum[tid]);
        atomicAdd(&stats1[(shard*32 + tid)*2 + 1], lsq[tid]);
    }
}

// ------------------------------------------------------------------
// KB: per-wave BN1 thresholds, binarize c1, conv2 xor+popc (lane=ch,
// fully unrolled), register BN2 stats, int8 o/2 out [n][ch][pos].
// 1 wave = 1 image; W from global; cw padded 17 (conflict-free).
// (R5-measured best form: 47.2 us)
// ------------------------------------------------------------------
__global__ __launch_bounds__(256) void kB_conv2(
    const int8_t* __restrict__ c1out, const int* __restrict__ stats1,
    const float* __restrict__ gm1, const float* __restrict__ bt1,
    const ull* __restrict__ w2bT,
    int8_t* __restrict__ c2out, ull* __restrict__ stats2)
{
    __shared__ ull BwU[4][14][8];       // packed input bits, per wave
    __shared__ int sT1[4][32];          // per-wave thresholds
    __shared__ uint32_t cw[4][64][17];  // staged out dwords, pad 17 -> no conflict
    __shared__ int ssum[64], ssq[64];
    const int tid = threadIdx.x, lane = tid & 63, wv = tid >> 6;
    const int n = blockIdx.x*4 + wv;

    // W fragments straight from global (coalesced, L2-hot)
    ull W[8];
    #pragma unroll
    for (int idx = 0; idx < 8; ++idx) W[idx] = w2bT[idx*64 + lane];

    if (tid < 64) { ssum[tid] = 0; ssq[tid] = 0; }
    // per-wave redundant BN1 threshold computation (lanes 0-31)
    int fl = 0;
    if (lane < 32) {
        long long s = 0, q = 0;
        for (int sh = 0; sh < 8; ++sh) {
            s += stats1[(sh*32 + lane)*2 + 0];
            q += stats1[(sh*32 + lane)*2 + 1];
        }
        const double N = 8192.0 * 196.0;
        const double mean = (double)s / N;
        const double var  = (double)q / N - mean*mean;
        const double a = (double)gm1[lane] / sqrt(var + 1e-5);
        const double b = (double)bt1[lane] - mean*a;
        int T; mk_thresh(a, b, T, fl);
        sT1[wv][lane] = clampT(T, 26);
    }
    const uint32_t flipn1 = ~(uint32_t)__ballot(fl != 0);
    __syncthreads();          // barrier 1: ssum zeros (thresholds wave-local)

    // pack phase — wave-local: binarize own image's 196 positions
    for (int t = lane; t < 196; t += 64) {
        const int r = t / 14, c = t - r*14;
        const uint4* src = (const uint4*)(c1out + ((size_t)n*196 + t)*32);
        const uint4 lo4 = src[0], hi4 = src[1];
        const uint32_t wsrc[8] = {lo4.x, lo4.y, lo4.z, lo4.w, hi4.x, hi4.y, hi4.z, hi4.w};
        uint32_t neg = 0u;
        #pragma unroll
        for (int d = 0; d < 8; ++d) {
            #pragma unroll
            for (int qq = 0; qq < 4; ++qq) {
                const int ch = d*4 + qq;
                const int v = (int)((int8_t)(wsrc[d] >> (8*qq)));
                neg |= ((uint32_t)(v - sT1[wv][ch]) >> 31) << ch;   // 1 iff v<T
            }
        }
        ((uint32_t*)&BwU[wv][r][0])[c] = neg ^ flipn1;
    }
    // compute phase — wave-local: lane = out-channel, unrolled 64 positions
    int s = 0, q = 0;
    #pragma unroll
    for (int i = 0; i < 8; ++i) {
        uint32_t packA = 0u;
        #pragma unroll
        for (int j = 0; j < 8; ++j) {
            int D = 0, nw = 0;
            #pragma unroll
            for (int u = 0; u < 4; ++u) {
                const int r = 2*i + u - 2;
                if (r < 0 || r > 13) continue;           // compile-time
                const ull* row = &BwU[wv][r][0];
                if (j >= 1) { D += __popcll(row[j-1] ^ W[2*u+0]); ++nw; }
                if (j <= 6) { D += __popcll(row[j]   ^ W[2*u+1]); ++nw; }
            }
            const int o = 32*nw - D;                     // = full/2, exact
            s += o; q += o*o;
            packA |= (uint32_t)(o & 255) << (8*(j & 3));
            if ((j & 3) == 3) { cw[wv][lane][2*i + (j >> 2)] = packA; packA = 0u; }
        }
    }
    atomicAdd(&ssum[lane], s);
    atomicAdd(&ssq[lane], q);
    {   // coalesced writeout [n][ch][pos] — wave-local, dword-wise
        uint32_t* dst = (uint32_t*)(c2out + (size_t)n*4096);
        #pragma unroll
        for (int t = 0; t < 16; ++t) {
            const int g = t*64 + lane;
            dst[g] = cw[wv][g >> 4][g & 15];
        }
    }
    __syncthreads();          // barrier 2: all waves' stats in ssum/ssq
    if (tid < 64) {
        const int shard = blockIdx.x & 7;
        atomicAdd(&stats2[(shard*64 + tid)*2 + 0], (ull)(long long)ssum[tid]);
        atomicAdd(&stats2[(shard*64 + tid)*2 + 1], (ull)(long long)ssq[tid]);
    }
}

// ------------------------------------------------------------------
// KC: per-lane BN2 thresholds (lane=ch, registers only), binarize
// arithmetically, fc xor+popc, packed shuffle reduction, BN3 stats.
// 1 wave = 1 image.
// ------------------------------------------------------------------
__global__ __launch_bounds__(256) void kC_fc(
    const int8_t* __restrict__ c2o, const float* __restrict__ gm2,
    const float* __restrict__ bt2, const ull* __restrict__ stats2,
    const ull* __restrict__ w3b,
    int* __restrict__ fc, ull* __restrict__ stats3)
{
    __shared__ int fco[4][10];
    __shared__ int s3[10], q3[10];
    const int tid = threadIdx.x, lane = tid & 63, wv = tid >> 6;
    if (tid < 10) { s3[tid] = 0; q3[tid] = 0; }
    // per-lane BN2 threshold for own channel (values stored are o/2)
    int T2, fl;
    {
        long long ss = 0, qq = 0;
        for (int sh = 0; sh < 8; ++sh) {
            ss += (long long)stats2[(sh*64 + lane)*2 + 0];
            qq += (long long)stats2[(sh*64 + lane)*2 + 1];
        }
        const double N = 8192.0 * 64.0;
        const double mh = (double)ss / N;
        const double vh = (double)qq / N - mh*mh;
        const double a = (double)gm2[lane] / sqrt(4.0*vh + 1e-5);
        const double b = (double)bt2[lane] - 2.0*mh*a;
        int T; mk_thresh(2.0*a, b, T, fl);
        T2 = clampT(T, 200);
    }
    const ull flipn2 = ~__ballot(fl != 0);
    const int n = blockIdx.x*4 + wv;
    // load own channel's 64 bytes, build bit-word arithmetically
    const uint4* src = (const uint4*)(c2o + (size_t)n*4096 + lane*64);
    uint32_t neglo = 0u, neghi = 0u;
    #pragma unroll
    for (int r4 = 0; r4 < 4; ++r4) {
        const uint4 v4 = src[r4];
        const uint32_t wsrc[4] = {v4.x, v4.y, v4.z, v4.w};
        #pragma unroll
        for (int cc = 0; cc < 4; ++cc) {
            #pragma unroll
            for (int b = 0; b < 4; ++b) {
                const int p = r4*16 + cc*4 + b;
                const int v = (int)((int8_t)(wsrc[cc] >> (8*b)));
                const uint32_t bit = (uint32_t)(v - T2) >> 31;   // 1 iff v<T
                if (p < 32) neglo |= bit << p; else neghi |= bit << (p - 32);
            }
        }
    }
    const ull myw = ((ull)neglo | ((ull)neghi << 32)) ^ flipn2;
    // 10 outputs: popc of mismatch vs w3 words (global, L2-hot), packed reduce
    uint32_t pk[5];
    #pragma unroll
    for (int t = 0; t < 5; ++t) {
        const uint32_t pa = (uint32_t)__popcll(myw ^ w3b[(2*t+0)*64 + lane]);
        const uint32_t pb = (uint32_t)__popcll(myw ^ w3b[(2*t+1)*64 + lane]);
        pk[t] = pa | (pb << 16);
    }
    #pragma unroll
    for (int off = 32; off >= 1; off >>= 1) {
        #pragma unroll
        for (int t = 0; t < 5; ++t) pk[t] += __shfl_xor(pk[t], off);
    }
    if (lane == 0) {
        #pragma unroll
        for (int m = 0; m < 10; ++m) {
            const int tot = (pk[m >> 1] >> (16*(m & 1))) & 0xFFFF;
            fco[wv][m] = 4096 - 2*tot;
        }
    }
    __syncthreads();
    if (tid < 40) {
        const int li = tid / 10, m = tid - li*10;
        const int o = fco[li][m];
        fc[(size_t)(blockIdx.x*4 + li)*10 + m] = o;
        atomicAdd(&s3[m], o);
        atomicAdd(&q3[m], o*o);
    }
    __syncthreads();
    if (tid < 10) {
        const int shard = blockIdx.x & 7;
        atomicAdd(&stats3[(shard*10 + tid)*2 + 0], (ull)(long long)s3[tid]);
        atomicAdd(&stats3[(shard*10 + tid)*2 + 1], (ull)(long long)q3[tid]);
    }
}

// ------------------------------------------------------------------
// KD: reduce BN3 stats (per block, redundant) + apply -> d_out (fp32)
// ------------------------------------------------------------------
__global__ __launch_bounds__(256) void kD_apply(
    const int* __restrict__ fc, const float* __restrict__ gm3,
    const float* __restrict__ bt3, const ull* __restrict__ stats3,
    float* __restrict__ out)
{
    __shared__ float a3[10], b3[10];
    const int tid = threadIdx.x;
    if (tid < 10) {
        long long s = 0, q = 0;
        for (int sh = 0; sh < 8; ++sh) {
            s += (long long)stats3[(sh*10 + tid)*2 + 0];
            q += (long long)stats3[(sh*10 + tid)*2 + 1];
        }
        const double N = 8192.0;
        const double mean = (double)s / N;
        const double var  = (double)q / N - mean*mean;
        const double a = (double)gm3[tid] / sqrt(var + 1e-5);
        a3[tid] = (float)a;
        b3[tid] = (float)((double)bt3[tid] - mean*a);
    }
    __syncthreads();
    const int e = blockIdx.x*256 + tid;
    if (e < NB*10) {
        const int m = e % 10;
        out[e] = fmaf(a3[m], (float)fc[e], b3[m]);
    }
}

extern "C" void kernel_launch(void* const* d_in, const int* in_sizes, int n_in,
                              void* d_out, int out_size, void* d_ws, size_t ws_size,
                              hipStream_t stream)
{
    const float* x   = (const float*)d_in[0];
    const float* w1  = (const float*)d_in[1];
    const float* gm1 = (const float*)d_in[2];
    const float* bt1 = (const float*)d_in[3];
    const float* w2  = (const float*)d_in[4];
    const float* gm2 = (const float*)d_in[5];
    const float* bt2 = (const float*)d_in[6];
    const float* w3  = (const float*)d_in[7];
    const float* gm3 = (const float*)d_in[8];
    const float* bt3 = (const float*)d_in[9];
    char* ws = (char*)d_ws;
    int8_t* c1o = (int8_t*)(ws + OFF_C1);
    int8_t* c2o = (int8_t*)(ws + OFF_C2);
    int*    fcb = (int*)(ws + OFF_FC);
    int*    s1  = (int*)(ws + OFF_S1);
    ull*    s2  = (ull*)(ws + OFF_S2);
    ull*    s3  = (ull*)(ws + OFF_S3);
    ull*    w2bp = (ull*)(ws + OFF_W2B);
    ull*    w3bp = (ull*)(ws + OFF_W3B);

    (void)hipMemsetAsync(ws + OFF_S1, 0, 12288, stream);
    kP_pack <<<5,    256, 0, stream>>>(w2, w3, w2bp, w3bp);
    kA_conv1<<<2048, 256, 0, stream>>>(x, w1, c1o, s1);
    kB_conv2<<<2048, 256, 0, stream>>>(c1o, s1, gm1, bt1, w2bp, c2o, s2);
    kC_fc   <<<2048, 256, 0, stream>>>(c2o, gm2, bt2, s2, w3bp, fcb, s3);
    kD_apply<<<320,  256, 0, stream>>>(fcb, gm3, bt3, s3, (float*)d_out);
}

// Round 10
// 181.445 us; speedup vs baseline: 2.2942x; 1.0062x over previous
//
#include <hip/hip_runtime.h>
#include <stdint.h>

// Binarized ConvNet via XOR+popcount on packed bits.
// BN stats = exact integer sums (sharded global atomics); BN+sign folded into
// exact per-channel integer thresholds, computed redundantly per consumer wave.
// kA conv1 (+5 early-exit weight-packer blocks); kB conv2 (b128 register
// sliding window + coalesced LDS-staged writeout); kC fc; kD BN3-apply.

#define NB 8192
typedef unsigned long long ull;

// ---- ws layout ----
#define OFF_C1  ((size_t)0)                    // int8 [NB][196pos][32ch]
#define SZ_C1   ((size_t)NB*6272)
#define OFF_C2  (OFF_C1 + SZ_C1)               // int8 [NB][64ch][64pos] (o/2)
#define SZ_C2   ((size_t)NB*4096)
#define OFF_FC  (OFF_C2 + SZ_C2)               // int32 [NB][10]
#define SZ_FC   ((size_t)NB*10*4)
#define OFF_S1  (OFF_FC + SZ_FC)               // int  [8][32][2]   2048 B
#define OFF_S2  (OFF_S1 + 2048)                // ull  [8][64][2]   8192 B
#define OFF_S3  (OFF_S2 + 8192)                // ull  [8][10][2]   (pad 2048)
#define OFF_W2B (OFF_S3 + 2048)                // ull w2bT[8][64] (word-idx major)
#define OFF_W3B (OFF_W2B + 4096)               // ull w3b[10][64ch], bit=pos

// exact integer threshold: bit = (v >= T) ^ flip  <=>  s*v + t > 0
__device__ inline void mk_thresh(double s, double t, int &T, int &flip) {
    if (s > 0.0) {
        int v = (int)floor(-t / s) - 2;
        for (int c = 0; c < 6; ++c) { if (s * (double)v + t > 0.0) break; ++v; }
        T = v; flip = 0;
    } else if (s < 0.0) {
        int v = (int)floor(-t / s) - 2;
        for (int c = 0; c < 6; ++c) { if (!(s * (double)v + t > 0.0)) break; ++v; }
        T = v; flip = 1;
    } else { T = -200; flip = (t > 0.0) ? 0 : 1; }
}
__device__ inline int clampT(int T, int lim) {
    return (T < -lim) ? -lim : (T > lim) ? lim : T;
}

// ------------------------------------------------------------------
// KA: conv1 (binary) + integer BN1 stats.  1 wave = 1 image, 4/block.
// Blocks >= 2048: weight packer, one THREAD per packed word (parallel).
// ------------------------------------------------------------------
__global__ __launch_bounds__(256) void kA_conv1(
    const float* __restrict__ x, const float* __restrict__ w1,
    const float* __restrict__ w2, const float* __restrict__ w3,
    int8_t* __restrict__ c1out, int* __restrict__ stats1,
    ull* __restrict__ w2bT, ull* __restrict__ w3b)
{
    const int tid = threadIdx.x, lane = tid & 63, wv = tid >> 6;

    if (blockIdx.x >= 2048) {   // ---- parallel weight packer blocks ----
        const int t = (blockIdx.x - 2048)*256 + tid;
        if (t < 512) {
            const int idx = t >> 6, k = t & 63;
            const int u = idx >> 1, pr = idx & 1;
            uint32_t lo = 0u, hi = 0u;
            #pragma unroll 8
            for (int c = 0; c < 32; ++c) {
                const float* wp = w2 + (((k*32 + c)*4 + u)*4 + 2*pr);
                lo |= (wp[0] > 0.f ? 1u : 0u) << c;
                hi |= (wp[1] > 0.f ? 1u : 0u) << c;
            }
            w2bT[t] = (ull)lo | ((ull)hi << 32);
        } else if (t < 1152) {
            const int w = t - 512;                 // w = m*64 + ch
            const float* wp = w3 + (size_t)(w >> 6)*4096 + (size_t)(w & 63)*64;
            ull bits = 0ull;
            #pragma unroll 16
            for (int k = 0; k < 64; ++k)
                bits |= (ull)(wp[k] > 0.f ? 1 : 0) << k;
            w3b[w] = bits;
        }
        return;
    }

    __shared__ ull sxb[4][16];              // 784 input sign bits, per wave
    __shared__ uint32_t wfilt[32];          // 25-bit filters
    __shared__ uint32_t outb[4][1568];      // int8 [196][32] as dwords, per wave
    __shared__ int lsum[32], lsq[32];

    if (tid < 32) {
        uint32_t f = 0u;
        #pragma unroll
        for (int q = 0; q < 25; ++q) f |= (w1[tid*25 + q] > 0.f ? 1u : 0u) << q;
        wfilt[tid] = f;
        lsum[tid] = 0; lsq[tid] = 0;
    }
    __syncthreads();          // barrier 1: wfilt + zeroed lsum visible
    const int n = blockIdx.x*4 + wv;
    // phase A: pack 784 input sign bits (13 ballot rounds) — wave-local
    #pragma unroll
    for (int t = 0; t < 13; ++t) {
        const int idx = t*64 + lane;
        const float v = (idx < 784) ? x[(size_t)n*784 + idx] : -1.f;
        const ull bal = __ballot(v > 0.f);
        if (lane == t) sxb[wv][t] = bal;
    }
    if (lane == 13) sxb[wv][13] = 0ull;
    // phase B: each lane computes up to 4 positions, 32 channels each
    for (int t = 0; t < 4; ++t) {
        const int p = t*64 + lane;
        if (p < 196) {
            const int i = p / 14, j = p - i*14;
            const uint32_t cmask = (j == 0) ? 0x1Cu : (j == 13) ? 0x0Fu : 0x1Fu;
            uint32_t win = 0u, vm = 0u;
            #pragma unroll
            for (int u = 0; u < 5; ++u) {
                const int r = 2*i + u - 2;
                if (r >= 0 && r < 28) {
                    const int bp = 28*r, w0 = bp >> 6, sh = bp & 63;
                    const ull a = sxb[wv][w0], b = sxb[wv][w0+1];
                    uint32_t row = (uint32_t)((a >> sh) | ((b << 1) << (63 - sh)));
                    row = (row & 0x0FFFFFFFu) << 2;
                    win |= ((row >> (2*j)) & 31u) << (5*u);
                    vm  |= cmask << (5*u);
                }
            }
            const int nv = __popc(vm);
            uint32_t dw[8];
            #pragma unroll
            for (int d = 0; d < 8; ++d) dw[d] = 0u;
            #pragma unroll
            for (int c = 0; c < 32; ++c) {
                const int diff = __popc((win ^ wfilt[c]) & vm);
                const int o = nv - 2*diff;
                dw[c >> 2] |= (uint32_t)(o & 255) << (8*(c & 3));
            }
            #pragma unroll
            for (int d = 0; d < 8; ++d) outb[wv][p*8 + d] = dw[d];
        }
    }
    {   // coalesced write [n][pos][ch] — wave-local, from LDS staging
        int4* dst = (int4*)(c1out + (size_t)n*6272);
        const int4* src = (const int4*)&outb[wv][0];
        #pragma unroll
        for (int t = 0; t < 7; ++t) {
            const int idx = t*64 + lane;
            if (idx < 392) dst[idx] = src[idx];
        }
    }
    {   // stats: dword reads, lane owns channel-dword d = lane&7
        int s4[4] = {0,0,0,0}, q4[4] = {0,0,0,0};
        const uint32_t* ob32 = &outb[wv][0];
        #pragma unroll
        for (int t = 0; t < 25; ++t) {
            const int idx = t*64 + lane;
            if (idx < 1568) {
                const uint32_t dwv = ob32[idx];
                #pragma unroll
                for (int qq = 0; qq < 4; ++qq) {
                    const int v = (int)((int8_t)(dwv >> (8*qq)));
                    s4[qq] += v; q4[qq] += v*v;
                }
            }
        }
        #pragma unroll
        for (int off = 8; off <= 32; off <<= 1) {
            #pragma unroll
            for (int qq = 0; qq < 4; ++qq) {
                s4[qq] += __shfl_xor(s4[qq], off);
                q4[qq] += __shfl_xor(q4[qq], off);
            }
        }
        if (lane < 8) {
            #pragma unroll
            for (int qq = 0; qq < 4; ++qq) {
                atomicAdd(&lsum[lane*4 + qq], s4[qq]);
                atomicAdd(&lsq[lane*4 + qq], q4[qq]);
            }
        }
    }
    __syncthreads();          // barrier 2: all waves' stats in lsum/lsq
    if (tid < 32) {
        const int shard = blockIdx.x & 7;
        atomicAdd(&stats1[(shard*32 + tid)*2 + 0], lsum[tid]);
        atomicAdd(&stats1[(shard*32 + tid)*2 + 1], lsq[tid]);
    }
}

// ------------------------------------------------------------------
// KB: per-wave BN1 thresholds, binarize c1, conv2 xor+popc with b128
// REGISTER sliding window (each row read once, broadcast), coalesced
// LDS-staged writeout, int8 o/2 out [n][ch][pos].  1 wave = 1 image.
// ------------------------------------------------------------------
__global__ __launch_bounds__(256) void kB_conv2(
    const int8_t* __restrict__ c1out, const int* __restrict__ stats1,
    const float* __restrict__ gm1, const float* __restrict__ bt1,
    const ull* __restrict__ w2bT,
    int8_t* __restrict__ c2out, ull* __restrict__ stats2)
{
    __shared__ uint32_t BwU[4][14][16]; // packed input bits, 14 used/row, pad 16
    __shared__ int sT1[4][32];          // per-wave thresholds
    __shared__ uint32_t cw[4][64][17];  // staged out dwords, pad 17 -> no conflict
    __shared__ int ssum[64], ssq[64];
    const int tid = threadIdx.x, lane = tid & 63, wv = tid >> 6;
    const int n = blockIdx.x*4 + wv;

    // W fragments from global (coalesced, L2-hot), split lo/hi dwords
    uint32_t Wlo[8], Whi[8];
    #pragma unroll
    for (int idx = 0; idx < 8; ++idx) {
        const uint2 w = ((const uint2*)w2bT)[idx*64 + lane];
        Wlo[idx] = w.x; Whi[idx] = w.y;
    }

    if (tid < 64) { ssum[tid] = 0; ssq[tid] = 0; }
    // per-wave redundant BN1 threshold computation (lanes 0-31)
    int fl = 0;
    if (lane < 32) {
        long long s = 0, q = 0;
        for (int sh = 0; sh < 8; ++sh) {
            s += stats1[(sh*32 + lane)*2 + 0];
            q += stats1[(sh*32 + lane)*2 + 1];
        }
        const double N = 8192.0 * 196.0;
        const double mean = (double)s / N;
        const double var  = (double)q / N - mean*mean;
        const double a = (double)gm1[lane] / sqrt(var + 1e-5);
        const double b = (double)bt1[lane] - mean*a;
        int T; mk_thresh(a, b, T, fl);
        sT1[wv][lane] = clampT(T, 26);
    }
    const uint32_t flipn1 = ~(uint32_t)__ballot(fl != 0);
    __syncthreads();          // barrier 1: ssum zeros (thresholds wave-local)

    // pack phase — wave-local: binarize own image's 196 positions
    for (int t = lane; t < 196; t += 64) {
        const int r = t / 14, c = t - r*14;
        const uint4* src = (const uint4*)(c1out + ((size_t)n*196 + t)*32);
        const uint4 lo4 = src[0], hi4 = src[1];
        const uint32_t wsrc[8] = {lo4.x, lo4.y, lo4.z, lo4.w, hi4.x, hi4.y, hi4.z, hi4.w};
        uint32_t neg = 0u;
        #pragma unroll
        for (int d = 0; d < 8; ++d) {
            #pragma unroll
            for (int qq = 0; qq < 4; ++qq) {
                const int ch = d*4 + qq;
                const int v = (int)((int8_t)(wsrc[d] >> (8*qq)));
                neg |= ((uint32_t)(v - sT1[wv][ch]) >> 31) << ch;   // 1 iff v<T
            }
        }
        BwU[wv][r][c] = neg ^ flipn1;
    }

    // compute phase: lane = out-channel; b128 register sliding window.
    // pair k = rows (2k, 2k+1); output row i uses pair i-1 (u=0,1) and pair i
    // (u=2,3).  Rows read ONCE via 4x ds_read_b128 each (wave-uniform bcast).
    uint32_t PA[32], PB[32];
#define LOADP(BUF, K)                                                          \
    {                                                                          \
        const uint4* r0 = (const uint4*)&BwU[wv][2*(K)][0];                    \
        const uint4* r1 = (const uint4*)&BwU[wv][2*(K)+1][0];                  \
        _Pragma("unroll")                                                      \
        for (int tt = 0; tt < 4; ++tt) {                                       \
            const uint4 v0 = r0[tt];                                           \
            BUF[4*tt+0] = v0.x; BUF[4*tt+1] = v0.y;                            \
            BUF[4*tt+2] = v0.z; BUF[4*tt+3] = v0.w;                            \
            const uint4 v1 = r1[tt];                                           \
            BUF[16+4*tt+0] = v1.x; BUF[16+4*tt+1] = v1.y;                      \
            BUF[16+4*tt+2] = v1.z; BUF[16+4*tt+3] = v1.w;                      \
        }                                                                      \
    }
#define UT(BUF, RO, UU)                                                        \
    {                                                                          \
        if (j >= 1) { D += __popc(BUF[(RO)*16 + 2*j-2] ^ Wlo[2*(UU)])          \
                         + __popc(BUF[(RO)*16 + 2*j-1] ^ Whi[2*(UU)]);   ++nw; } \
        if (j <= 6) { D += __popc(BUF[(RO)*16 + 2*j]   ^ Wlo[2*(UU)+1])        \
                         + __popc(BUF[(RO)*16 + 2*j+1] ^ Whi[2*(UU)+1]); ++nw; } \
    }
    int s = 0, q = 0;
    LOADP(PA, 0)
    #pragma unroll
    for (int i = 0; i < 8; ++i) {
        if (i >= 1 && i <= 6) {      // prefetch pair i into alternating buffer
            if (i & 1) { LOADP(PB, i) } else { LOADP(PA, i) }
        }
        uint32_t o0 = 0u, o1 = 0u;
        #pragma unroll
        for (int j = 0; j < 8; ++j) {
            int D = 0, nw = 0;
            if (i >= 1) {            // pair i-1: rows 2i-2 (u=0), 2i-1 (u=1)
                if ((i-1) & 1) { UT(PB, 0, 0) UT(PB, 1, 1) }
                else           { UT(PA, 0, 0) UT(PA, 1, 1) }
            }
            if (i <= 6) {            // pair i:   rows 2i (u=2), 2i+1 (u=3)
                if (i & 1) { UT(PB, 0, 2) UT(PB, 1, 3) }
                else       { UT(PA, 0, 2) UT(PA, 1, 3) }
            }
            const int o = 32*nw - D;         // = full/2, exact
            s += o; q += o*o;
            if (j < 4) o0 |= (uint32_t)(o & 255) << (8*j);
            else       o1 |= (uint32_t)(o & 255) << (8*(j-4));
        }
        cw[wv][lane][2*i]     = o0;
        cw[wv][lane][2*i + 1] = o1;
    }
#undef LOADP
#undef UT
    atomicAdd(&ssum[lane], s);
    atomicAdd(&ssq[lane], q);
    {   // coalesced writeout [n][ch][pos] — wave-local, dword-wise
        uint32_t* dst = (uint32_t*)(c2out + (size_t)n*4096);
        #pragma unroll
        for (int t = 0; t < 16; ++t) {
            const int g = t*64 + lane;
            dst[g] = cw[wv][g >> 4][g & 15];
        }
    }
    __syncthreads();          // barrier 2: all waves' stats in ssum/ssq
    if (tid < 64) {
        const int shard = blockIdx.x & 7;
        atomicAdd(&stats2[(shard*64 + tid)*2 + 0], (ull)(long long)ssum[tid]);
        atomicAdd(&stats2[(shard*64 + tid)*2 + 1], (ull)(long long)ssq[tid]);
    }
}

// ------------------------------------------------------------------
// KC: per-lane BN2 thresholds (lane=ch, registers only), binarize
// arithmetically, fc xor+popc, packed shuffle reduction, BN3 stats.
// 1 wave = 1 image.
// ------------------------------------------------------------------
__global__ __launch_bounds__(256) void kC_fc(
    const int8_t* __restrict__ c2o, const float* __restrict__ gm2,
    const float* __restrict__ bt2, const ull* __restrict__ stats2,
    const ull* __restrict__ w3b,
    int* __restrict__ fc, ull* __restrict__ stats3)
{
    __shared__ int fco[4][10];
    __shared__ int s3[10], q3[10];
    const int tid = threadIdx.x, lane = tid & 63, wv = tid >> 6;
    if (tid < 10) { s3[tid] = 0; q3[tid] = 0; }
    // per-lane BN2 threshold for own channel (values stored are o/2)
    int T2, fl;
    {
        long long ss = 0, qq = 0;
        for (int sh = 0; sh < 8; ++sh) {
            ss += (long long)stats2[(sh*64 + lane)*2 + 0];
            qq += (long long)stats2[(sh*64 + lane)*2 + 1];
        }
        const double N = 8192.0 * 64.0;
        const double mh = (double)ss / N;
        const double vh = (double)qq / N - mh*mh;
        const double a = (double)gm2[lane] / sqrt(4.0*vh + 1e-5);
        const double b = (double)bt2[lane] - 2.0*mh*a;
        int T; mk_thresh(2.0*a, b, T, fl);
        T2 = clampT(T, 200);
    }
    const ull flipn2 = ~__ballot(fl != 0);
    const int n = blockIdx.x*4 + wv;
    // load own channel's 64 bytes, build bit-word arithmetically
    const uint4* src = (const uint4*)(c2o + (size_t)n*4096 + lane*64);
    uint32_t neglo = 0u, neghi = 0u;
    #pragma unroll
    for (int r4 = 0; r4 < 4; ++r4) {
        const uint4 v4 = src[r4];
        const uint32_t wsrc[4] = {v4.x, v4.y, v4.z, v4.w};
        #pragma unroll
        for (int cc = 0; cc < 4; ++cc) {
            #pragma unroll
            for (int b = 0; b < 4; ++b) {
                const int p = r4*16 + cc*4 + b;
                const int v = (int)((int8_t)(wsrc[cc] >> (8*b)));
                const uint32_t bit = (uint32_t)(v - T2) >> 31;   // 1 iff v<T
                if (p < 32) neglo |= bit << p; else neghi |= bit << (p - 32);
            }
        }
    }
    const ull myw = ((ull)neglo | ((ull)neghi << 32)) ^ flipn2;
    // 10 outputs: popc of mismatch vs w3 words (global, L2-hot), packed reduce
    uint32_t pk[5];
    #pragma unroll
    for (int t = 0; t < 5; ++t) {
        const uint32_t pa = (uint32_t)__popcll(myw ^ w3b[(2*t+0)*64 + lane]);
        const uint32_t pb = (uint32_t)__popcll(myw ^ w3b[(2*t+1)*64 + lane]);
        pk[t] = pa | (pb << 16);
    }
    #pragma unroll
    for (int off = 32; off >= 1; off >>= 1) {
        #pragma unroll
        for (int t = 0; t < 5; ++t) pk[t] += __shfl_xor(pk[t], off);
    }
    if (lane == 0) {
        #pragma unroll
        for (int m = 0; m < 10; ++m) {
            const int tot = (pk[m >> 1] >> (16*(m & 1))) & 0xFFFF;
            fco[wv][m] = 4096 - 2*tot;
        }
    }
    __syncthreads();
    if (tid < 40) {
        const int li = tid / 10, m = tid - li*10;
        const int o = fco[li][m];
        fc[(size_t)(blockIdx.x*4 + li)*10 + m] = o;
        atomicAdd(&s3[m], o);
        atomicAdd(&q3[m], o*o);
    }
    __syncthreads();
    if (tid < 10) {
        const int shard = blockIdx.x & 7;
        atomicAdd(&stats3[(shard*10 + tid)*2 + 0], (ull)(long long)s3[tid]);
        atomicAdd(&stats3[(shard*10 + tid)*2 + 1], (ull)(long long)q3[tid]);
    }
}

// ------------------------------------------------------------------
// KD: reduce BN3 stats (per block, redundant) + apply -> d_out (fp32)
// ------------------------------------------------------------------
__global__ __launch_bounds__(256) void kD_apply(
    const int* __restrict__ fc, const float* __restrict__ gm3,
    const float* __restrict__ bt3, const ull* __restrict__ stats3,
    float* __restrict__ out)
{
    __shared__ float a3[10], b3[10];
    const int tid = threadIdx.x;
    if (tid < 10) {
        long long s = 0, q = 0;
        for (int sh = 0; sh < 8; ++sh) {
            s += (long long)stats3[(sh*10 + tid)*2 + 0];
            q += (long long)stats3[(sh*10 + tid)*2 + 1];
        }
        const double N = 8192.0;
        const double mean = (double)s / N;
        const double var  = (double)q / N - mean*mean;
        const double a = (double)gm3[tid] / sqrt(var + 1e-5);
        a3[tid] = (float)a;
        b3[tid] = (float)((double)bt3[tid] - mean*a);
    }
    __syncthreads();
    const int e = blockIdx.x*256 + tid;
    if (e < NB*10) {
        const int m = e % 10;
        out[e] = fmaf(a3[m], (float)fc[e], b3[m]);
    }
}

extern "C" void kernel_launch(void* const* d_in, const int* in_sizes, int n_in,
                              void* d_out, int out_size, void* d_ws, size_t ws_size,
                              hipStream_t stream)
{
    const float* x   = (const float*)d_in[0];
    const float* w1  = (const float*)d_in[1];
    const float* gm1 = (const float*)d_in[2];
    const float* bt1 = (const float*)d_in[3];
    const float* w2  = (const float*)d_in[4];
    const float* gm2 = (const float*)d_in[5];
    const float* bt2 = (const float*)d_in[6];
    const float* w3  = (const float*)d_in[7];
    const float* gm3 = (const float*)d_in[8];
    const float* bt3 = (const float*)d_in[9];
    char* ws = (char*)d_ws;
    int8_t* c1o = (int8_t*)(ws + OFF_C1);
    int8_t* c2o = (int8_t*)(ws + OFF_C2);
    int*    fcb = (int*)(ws + OFF_FC);
    int*    s1  = (int*)(ws + OFF_S1);
    ull*    s2  = (ull*)(ws + OFF_S2);
    ull*    s3  = (ull*)(ws + OFF_S3);
    ull*    w2bp = (ull*)(ws + OFF_W2B);
    ull*    w3bp = (ull*)(ws + OFF_W3B);

    (void)hipMemsetAsync(ws + OFF_S1, 0, 12288, stream);
    kA_conv1<<<2053, 256, 0, stream>>>(x, w1, w2, w3, c1o, s1, w2bp, w3bp);
    kB_conv2<<<2048, 256, 0, stream>>>(c1o, s1, gm1, bt1, w2bp, c2o, s2);
    kC_fc   <<<2048, 256, 0, stream>>>(c2o, gm2, bt2, s2, w3bp, fcb, s3);
    kD_apply<<<320,  256, 0, stream>>>(fcb, gm3, bt3, s3, (float*)d_out);
}